// Round 7
// baseline (382.127 us; speedup 1.0000x reference)
//
#include <hip/hip_runtime.h>
#include <stdint.h>

typedef float f32x4 __attribute__((ext_vector_type(4)));
typedef float f32x16 __attribute__((ext_vector_type(16)));
typedef __bf16 bf16x8 __attribute__((ext_vector_type(8)));
typedef unsigned short u16;
typedef unsigned int u32;

#define INVT 14.285714285714286f   // 1/0.07 ; also the fixed LSE max bound (cos<=1)
#define L2E  1.4426950408889634f

__device__ __forceinline__ u16 f2bf(float f) {
  u32 u = __float_as_uint(f);
  u32 r = (u + 0x7fffu + ((u >> 16) & 1u)) >> 16;
  return (u16)r;
}
__device__ __forceinline__ float bf2f(u16 h) { return __uint_as_float(((u32)h) << 16); }

// async global->LDS, 16B per lane (lane i lands at base + i*16)
__device__ __forceinline__ void g2l16(const void* g, void* l) {
  auto gp = reinterpret_cast<__attribute__((address_space(1))) uint32_t*>(
      reinterpret_cast<uintptr_t>(g));
  auto lp = reinterpret_cast<__attribute__((address_space(3))) uint32_t*>(
      reinterpret_cast<uintptr_t>(l));
  __builtin_amdgcn_global_load_lds(gp, lp, 16, 0, 0);
}

// ---------- fp32 -> bf16 convert, both inputs in one launch ----------
__global__ __launch_bounds__(256) void k_cvt2(const float* __restrict__ in1,
                                              const float* __restrict__ in2,
                                              u16* __restrict__ out) {
  int i = (blockIdx.x * 256 + threadIdx.x) * 4;
  float4 v;
  if (i < 8388608) v = *(const float4*)(in1 + i);
  else             v = *(const float4*)(in2 + (i - 8388608));
  ushort4 p;
  p.x = f2bf(v.x); p.y = f2bf(v.y); p.z = f2bf(v.z); p.w = f2bf(v.w);
  *(ushort4*)(out + i) = p;
}

// ---------- fp32 [R][C] -> bf16 [C][R] transpose (z selects W0/W1) ----------
__global__ __launch_bounds__(256) void k_transpose2(const float* __restrict__ w0,
                                                    u16* __restrict__ w0t,
                                                    const float* __restrict__ w1,
                                                    u16* __restrict__ w1t) {
  const float* in = blockIdx.z ? w1 : w0;
  u16* out = blockIdx.z ? w1t : w0t;
  const int R = 2048, C = 2048;
  __shared__ float t[64][65];
  const int r0 = blockIdx.y * 64, c0 = blockIdx.x * 64;
#pragma unroll
  for (int p = 0; p < 16; ++p) {
    int idx = p * 256 + threadIdx.x;
    int r = idx >> 6, c = idx & 63;
    t[r][c] = in[(size_t)(r0 + r) * C + (c0 + c)];
  }
  __syncthreads();
#pragma unroll
  for (int p = 0; p < 16; ++p) {
    int idx = p * 256 + threadIdx.x;
    int c = idx >> 6, r = idx & 63;
    out[(size_t)(c0 + c) * R + (r0 + r)] = f2bf(t[r][c]);
  }
}

__global__ __launch_bounds__(256) void k_transpose(const float* __restrict__ in,
                                                   u16* __restrict__ out, int R, int C) {
  __shared__ float t[64][65];
  const int r0 = blockIdx.y * 64, c0 = blockIdx.x * 64;
#pragma unroll
  for (int p = 0; p < 16; ++p) {
    int idx = p * 256 + threadIdx.x;
    int r = idx >> 6, c = idx & 63;
    t[r][c] = in[(size_t)(r0 + r) * C + (c0 + c)];
  }
  __syncthreads();
#pragma unroll
  for (int p = 0; p < 16; ++p) {
    int idx = p * 256 + threadIdx.x;
    int c = idx >> 6, r = idx & 63;
    out[(size_t)(c0 + c) * R + (r0 + r)] = f2bf(t[r][c]);
  }
}

// ---------- bf16 GEMM: C = op(A @ Bt^T + bias) ----------
// 256x128 block tile, BK=32, 2 WAVES (128 threads), wave tile 128x128 via
// 4x4 of 32x32x16 MFMA: 16 ds_read_b128 per 32 MFMA (0.5 reads/MFMA).
// 3-stage LDS pipeline (72KB -> 2 blk/CU, 4 waves/CU, 1/SIMD), 1 barrier/step:
//   [wait vmcnt(12)][s_barrier][issue k+2][compute k]
// Two independent co-resident blocks decouple barrier stalls (round-6 lesson:
// 1 blk/CU regressed).
__global__ __launch_bounds__(128, 1) void k_gemm(const u16* __restrict__ A, const u16* __restrict__ Bt,
                                                 const float* __restrict__ bias, u16* __restrict__ C,
                                                 int M, int N, int K, int relu) {
  __shared__ __align__(16) u16 sm[36864];  // 3 stages x (A 256x32 16KB | B 128x32 8KB)
  const int tid = threadIdx.x;
  const int l = tid & 63, w2 = tid >> 6;   // 2 waves
  const int m0 = blockIdx.y * 256, n0 = blockIdx.x * 128;

  // staging: 24 x 1KB chunks/stage (16 A rows 0..255, 8 B rows 0..127), 16
  // rows/chunk; wave w2 handles chunks w2*12 + j. lane l -> row l>>2 within
  // chunk, phys 16B piece l&3, xor-swizzled by row.
  const int kb = ((l & 3) ^ ((l >> 3) & 3)) * 16;
  const char* gA = (const char*)(A + (size_t)(m0 + (l >> 2)) * K) + kb;
  const char* gB = (const char*)(Bt + (size_t)(n0 + (l >> 2)) * K) + kb;
  const size_t chRows = (size_t)16 * K * 2;  // 16-row chunk stride (bytes)

  auto issue = [&](int kcB, int stg) {
    char* dst = (char*)sm + stg * 24576 + (w2 * 12) * 1024 + l * 16;
#pragma unroll
    for (int j = 0; j < 12; ++j) {
      const int c = w2 * 12 + j;
      const char* s = (c < 16) ? (gA + (size_t)c * chRows + kcB)
                               : (gB + (size_t)(c - 16) * chRows + kcB);
      g2l16(s, dst + j * 1024);
    }
  };

  const int lm = l & 31;
  const int c0 = l >> 5;
  const int sw = (lm >> 1) & 3;

  f32x16 acc[4][4] = {};

  auto compute = [&](int stg) {
    const u16* As = sm + stg * 12288;
    const u16* Bs = As + 8192;
#pragma unroll
    for (int t = 0; t < 2; ++t) {
      const int cc = (((t << 1) + c0) ^ sw) * 8;
      bf16x8 a4[4], b4[4];
#pragma unroll
      for (int fm = 0; fm < 4; ++fm)
        a4[fm] = *(const bf16x8*)(As + (w2 * 128 + fm * 32 + lm) * 32 + cc);
#pragma unroll
      for (int fn = 0; fn < 4; ++fn)
        b4[fn] = *(const bf16x8*)(Bs + (fn * 32 + lm) * 32 + cc);
#pragma unroll
      for (int fm = 0; fm < 4; ++fm)
#pragma unroll
        for (int fn = 0; fn < 4; ++fn)
          acc[fm][fn] = __builtin_amdgcn_mfma_f32_32x32x16_bf16(a4[fm], b4[fn],
                                                                acc[fm][fn], 0, 0, 0);
    }
  };

  const int NK = K >> 5;
  issue(0, 0);
  issue(64, 1);
  int st = 0;
  for (int kt = 0; kt < NK; ++kt) {
    if (kt + 1 < NK) asm volatile("s_waitcnt vmcnt(12)" ::: "memory");
    else             asm volatile("s_waitcnt vmcnt(0)" ::: "memory");
    asm volatile("s_barrier" ::: "memory");
    if (kt + 2 < NK) {
      int stp = st + 2; if (stp >= 3) stp -= 3;
      issue((kt + 2) * 64, stp);
    }
    compute(st);
    ++st; if (st == 3) st = 0;
  }

  // C/D 32x32: col = lane&31, row = (reg&3) + 8*(reg>>2) + 4*(lane>>5)
  const int colb = n0 + lm;
  const int rowb = m0 + w2 * 128 + 4 * c0;
#pragma unroll
  for (int fn = 0; fn < 4; ++fn) {
    const float b = bias[colb + fn * 32];
#pragma unroll
    for (int fm = 0; fm < 4; ++fm)
#pragma unroll
      for (int g = 0; g < 4; ++g)
#pragma unroll
        for (int rr = 0; rr < 4; ++rr) {
          float v = acc[fm][fn][g * 4 + rr] + b;
          if (relu) v = fmaxf(v, 0.0f);
          C[(size_t)(rowb + fm * 32 + g * 8 + rr) * N + colb + fn * 32] = f2bf(v);
        }
  }
}

// ---------- fused GEMM2 + bias + L2-normalize: F[8192][128] bf16 ----------
// grid 512, block = 16 rows x 128 cols, K=2048. No LDS staging, no barriers:
// A-frags (block-shared 16 rows -> L1 hits) and B-frags (W2T 512KB, L2
// resident) are direct b128 register gathers; 2 MFMA (16x16x32) per k-step.
__global__ __launch_bounds__(256, 2) void k_embed(const u16* __restrict__ H, const u16* __restrict__ Bt,
                                                  const float* __restrict__ b2, u16* __restrict__ F) {
  const int tid = threadIdx.x;
  const int l = tid & 63, w = tid >> 6;
  const int m = l & 15, kq = l >> 4;
  const int r0 = blockIdx.x * 16;

  const char* pA = (const char*)(H + (size_t)(r0 + m) * 2048) + kq * 16;
  const char* pB0 = (const char*)(Bt + (size_t)(w * 32 + m) * 2048) + kq * 16;
  const char* pB1 = pB0 + (size_t)16 * 2048 * 2;

  f32x4 acc0 = {}, acc1 = {};
#pragma unroll 8
  for (int k = 0; k < 64; ++k) {
    bf16x8 av = *(const bf16x8*)(pA + k * 64);
    bf16x8 b0 = *(const bf16x8*)(pB0 + k * 64);
    bf16x8 b1 = *(const bf16x8*)(pB1 + k * 64);
    acc0 = __builtin_amdgcn_mfma_f32_16x16x32_bf16(av, b0, acc0, 0, 0, 0);
    acc1 = __builtin_amdgcn_mfma_f32_16x16x32_bf16(av, b1, acc1, 0, 0, 0);
  }

  // bias + row sum-of-squares. C/D 16x16: col = lane&15, row = kq*4 + reg.
  const float vb0 = b2[w * 32 + m], vb1 = b2[w * 32 + 16 + m];
  float v0[4], v1[4], s[4];
#pragma unroll
  for (int r = 0; r < 4; ++r) {
    v0[r] = acc0[r] + vb0;
    v1[r] = acc1[r] + vb1;
    s[r] = v0[r] * v0[r] + v1[r] * v1[r];
  }
#pragma unroll
  for (int off = 1; off < 16; off <<= 1)
#pragma unroll
    for (int r = 0; r < 4; ++r) s[r] += __shfl_xor(s[r], off);

  __shared__ float red[4][16];
  if (m == 0) {
#pragma unroll
    for (int r = 0; r < 4; ++r) red[w][kq * 4 + r] = s[r];
  }
  __syncthreads();
#pragma unroll
  for (int r = 0; r < 4; ++r) {
    const int row = kq * 4 + r;
    const float inv = rsqrtf(red[0][row] + red[1][row] + red[2][row] + red[3][row]);
    F[(size_t)(r0 + row) * 128 + w * 32 + m] = f2bf(v0[r] * inv);
    F[(size_t)(r0 + row) * 128 + w * 32 + 16 + m] = f2bf(v1[r] * inv);
  }
}

// ---------- fused sim GEMM + fixed-max sumexp, register-cached A ----------
__global__ __launch_bounds__(256, 2) void k_sim(const u16* __restrict__ F, float* __restrict__ Sp) {
  __shared__ __align__(16) u16 sm[32768];  // [B0 32KB][A/B1 32KB]
  const int tid = threadIdx.x;
  const int l = tid & 63, w = tid >> 6;
  const int wm = w >> 1, wn = w & 1;
  const int lm = l & 31, c0 = l >> 5;
  const int r0 = blockIdx.y * 128;
  const int cb0 = blockIdx.x * 1024;

  u16* B0 = sm;
  u16* AB1 = sm + 16384;

  const int srow0 = tid >> 4;
  const int schunk = tid & 15;
  auto stage = [&](const u16* src, u16* dst) {
#pragma unroll
    for (int j = 0; j < 8; ++j) {
      const int row = j * 16 + srow0;
      const int lc = schunk ^ (row & 7);
      g2l16((const char*)(src + (size_t)row * 128) + lc * 16,
            (char*)dst + j * 4096 + tid * 16);
    }
  };

  stage(F + (size_t)r0 * 128, AB1);
  asm volatile("s_waitcnt vmcnt(0)" ::: "memory");
  __syncthreads();

  bf16x8 a[2][8];
#pragma unroll
  for (int fm = 0; fm < 2; ++fm) {
    const int ra = wm * 64 + fm * 32 + lm;
#pragma unroll
    for (int kf = 0; kf < 8; ++kf)
      a[fm][kf] = *(const bf16x8*)(AB1 + ra * 128 + (((kf << 1) + c0) ^ (ra & 7)) * 8);
  }
  asm volatile("s_waitcnt lgkmcnt(0)" ::: "memory");

  stage(F + (size_t)cb0 * 128, B0);

  const float S2 = INVT * L2E;
  const int rB = wn * 64 + lm;
  f32x16 runS[2] = {};

#pragma unroll 1
  for (int p = 0; p < 8; ++p) {
    asm volatile("s_waitcnt vmcnt(0)" ::: "memory");
    asm volatile("s_barrier" ::: "memory");
    if (p < 7) stage(F + (size_t)(cb0 + (p + 1) * 128) * 128, (p & 1) ? B0 : AB1);
    const u16* Bs = (p & 1) ? AB1 : B0;

    f32x16 acc[2][2] = {};
#pragma unroll
    for (int kf = 0; kf < 8; ++kf) {
      const int kc = (kf << 1) + c0;
      bf16x8 b0v = *(const bf16x8*)(Bs + rB * 128 + (kc ^ (rB & 7)) * 8);
      bf16x8 b1v = *(const bf16x8*)(Bs + (rB + 32) * 128 + (kc ^ ((rB + 32) & 7)) * 8);
      acc[0][0] = __builtin_amdgcn_mfma_f32_32x32x16_bf16(a[0][kf], b0v, acc[0][0], 0, 0, 0);
      acc[0][1] = __builtin_amdgcn_mfma_f32_32x32x16_bf16(a[0][kf], b1v, acc[0][1], 0, 0, 0);
      acc[1][0] = __builtin_amdgcn_mfma_f32_32x32x16_bf16(a[1][kf], b0v, acc[1][0], 0, 0, 0);
      acc[1][1] = __builtin_amdgcn_mfma_f32_32x32x16_bf16(a[1][kf], b1v, acc[1][1], 0, 0, 0);
    }

    const int cp = cb0 + p * 128;
    if (cp == r0) {
#pragma unroll
      for (int fm = 0; fm < 2; ++fm)
#pragma unroll
        for (int fn = 0; fn < 2; ++fn) {
          const int rcol = wn * 64 + fn * 32 + lm;
#pragma unroll
          for (int r = 0; r < 16; ++r) {
            const int rrow = wm * 64 + fm * 32 + (r & 3) + 8 * (r >> 2) + 4 * c0;
            float e = exp2f(fmaf(acc[fm][fn][r], S2, -S2));
            if (rrow == rcol) e = 0.f;
            runS[fm][r] += e;
          }
        }
    } else {
#pragma unroll
      for (int fm = 0; fm < 2; ++fm)
#pragma unroll
        for (int fn = 0; fn < 2; ++fn)
#pragma unroll
          for (int r = 0; r < 16; ++r)
            runS[fm][r] += exp2f(fmaf(acc[fm][fn][r], S2, -S2));
    }
  }

#pragma unroll
  for (int fm = 0; fm < 2; ++fm)
#pragma unroll
    for (int r = 0; r < 16; ++r) {
      float s = runS[fm][r];
      s += __shfl_xor(s, 1);
      s += __shfl_xor(s, 2);
      s += __shfl_xor(s, 4);
      s += __shfl_xor(s, 8);
      s += __shfl_xor(s, 16);
      runS[fm][r] = s;
    }

  __syncthreads();
  float* red = (float*)sm;
  if (wn == 0) {
    if (lm == 0) {
#pragma unroll
      for (int fm = 0; fm < 2; ++fm)
#pragma unroll
        for (int r = 0; r < 16; ++r)
          red[wm * 64 + fm * 32 + (r & 3) + 8 * (r >> 2) + 4 * c0] = runS[fm][r];
    }
  }
  __syncthreads();
  if (wn == 1 && lm == 0) {
#pragma unroll
    for (int fm = 0; fm < 2; ++fm)
#pragma unroll
      for (int r = 0; r < 16; ++r) {
        const int rr = wm * 64 + fm * 32 + (r & 3) + 8 * (r >> 2) + 4 * c0;
        Sp[(size_t)blockIdx.x * 8192 + r0 + rr] = red[rr] + runS[fm][r];
      }
  }
}

// ---------- merge chunk partials, compute pos, reduce mean(lse - pos) ----------
__global__ __launch_bounds__(256) void k_combine(const float* __restrict__ Sp,
                                                 const u16* __restrict__ F,
                                                 float* __restrict__ out) {
  const int r = blockIdx.x * 256 + threadIdx.x;
  float S = 0.f;
#pragma unroll
  for (int c = 0; c < 8; ++c) S += Sp[c * 8192 + r];
  const float lse = INVT + logf(S);
  const int par = (r + 4096) & 8191;
  const u16* a = F + (size_t)r * 128;
  const u16* b = F + (size_t)par * 128;
  float dot = 0.f;
#pragma unroll 8
  for (int k = 0; k < 128; ++k) dot = fmaf(bf2f(a[k]), bf2f(b[k]), dot);
  float contrib = lse - dot * INVT;
#pragma unroll
  for (int off = 1; off < 64; off <<= 1) contrib += __shfl_xor(contrib, off);
  if ((threadIdx.x & 63) == 0) atomicAdd(out, contrib * (1.0f / 8192.0f));
}

extern "C" void kernel_launch(void* const* d_in, const int* in_sizes, int n_in,
                              void* d_out, int out_size, void* d_ws, size_t ws_size,
                              hipStream_t stream) {
  const float* input1 = (const float*)d_in[0];
  const float* input2 = (const float*)d_in[1];
  const float* W0 = (const float*)d_in[2];
  const float* b0 = (const float*)d_in[3];
  const float* W1 = (const float*)d_in[4];
  const float* b1 = (const float*)d_in[5];
  const float* W2 = (const float*)d_in[6];
  const float* b2 = (const float*)d_in[7];
  float* out = (float*)d_out;
  char* ws = (char*)d_ws;

  u16* Xb = (u16*)(ws + 0);              // [8192][2048] bf16; reused as H2
  u16* H1 = (u16*)(ws + 33554432);
  u16* W0T = (u16*)(ws + 67108864);
  u16* W1T = (u16*)(ws + 75497472);
  u16* W2T = (u16*)(ws + 83886080);
  float* Sp = (float*)(ws + 83886080);   // [8][8192] fp32, overlays dead W2T
  u16* Ff = (u16*)(ws + 84410368);
  u16* H2 = Xb;

  hipMemsetAsync(d_out, 0, sizeof(float), stream);
  k_cvt2<<<16384, 256, 0, stream>>>(input1, input2, Xb);
  k_transpose2<<<dim3(32, 32, 2), 256, 0, stream>>>(W0, W0T, W1, W1T);
  k_transpose<<<dim3(2, 32), 256, 0, stream>>>(W2, W2T, 2048, 128);
  k_gemm<<<dim3(16, 32), 128, 0, stream>>>(Xb, W0T, b0, H1, 8192, 2048, 2048, 1);
  k_gemm<<<dim3(16, 32), 128, 0, stream>>>(H1, W1T, b1, H2, 8192, 2048, 2048, 0);
  k_embed<<<512, 256, 0, stream>>>(H2, W2T, b2, Ff);
  k_sim<<<dim3(8, 64), 256, 0, stream>>>(Ff, Sp);
  k_combine<<<32, 256, 0, stream>>>(Sp, Ff, out);
}

// Round 8
// 345.052 us; speedup vs baseline: 1.1074x; 1.1074x over previous
//
#include <hip/hip_runtime.h>
#include <stdint.h>

typedef float f32x4 __attribute__((ext_vector_type(4)));
typedef float f32x16 __attribute__((ext_vector_type(16)));
typedef __bf16 bf16x8 __attribute__((ext_vector_type(8)));
typedef unsigned short u16;
typedef unsigned int u32;

#define INVT 14.285714285714286f   // 1/0.07 ; also the fixed LSE max bound (cos<=1)
#define L2E  1.4426950408889634f

__device__ __forceinline__ u16 f2bf(float f) {
  u32 u = __float_as_uint(f);
  u32 r = (u + 0x7fffu + ((u >> 16) & 1u)) >> 16;
  return (u16)r;
}
__device__ __forceinline__ float bf2f(u16 h) { return __uint_as_float(((u32)h) << 16); }

// async global->LDS, 16B per lane (lane i lands at base + i*16)
__device__ __forceinline__ void g2l16(const void* g, void* l) {
  auto gp = reinterpret_cast<__attribute__((address_space(1))) uint32_t*>(
      reinterpret_cast<uintptr_t>(g));
  auto lp = reinterpret_cast<__attribute__((address_space(3))) uint32_t*>(
      reinterpret_cast<uintptr_t>(l));
  __builtin_amdgcn_global_load_lds(gp, lp, 16, 0, 0);
}

// ---------- fused prep: fp32->bf16 convert of both inputs + W0/W1/W2 transposes ----------
// flat grid role split: [0,16384) cvt; [16384,18432) W0/W1 transpose; [18432,18496) W2.
__global__ __launch_bounds__(256) void k_prep(const float* __restrict__ in1,
                                              const float* __restrict__ in2,
                                              u16* __restrict__ Xb,
                                              const float* __restrict__ w0, u16* __restrict__ w0t,
                                              const float* __restrict__ w1, u16* __restrict__ w1t,
                                              const float* __restrict__ w2, u16* __restrict__ w2t) {
  const int bid = blockIdx.x;
  if (bid < 16384) {
    int i = (bid * 256 + threadIdx.x) * 4;
    float4 v;
    if (i < 8388608) v = *(const float4*)(in1 + i);
    else             v = *(const float4*)(in2 + (i - 8388608));
    ushort4 p;
    p.x = f2bf(v.x); p.y = f2bf(v.y); p.z = f2bf(v.z); p.w = f2bf(v.w);
    *(ushort4*)(Xb + i) = p;
    return;
  }
  __shared__ float t[64][65];
  const float* in; u16* out; int R, C, r0, c0;
  if (bid < 18432) {
    const int f = bid - 16384;
    const int z = f >> 10, rem = f & 1023;
    in = z ? w1 : w0; out = z ? w1t : w0t; R = 2048; C = 2048;
    r0 = (rem >> 5) * 64; c0 = (rem & 31) * 64;
  } else {
    const int f = bid - 18432;
    in = w2; out = w2t; R = 2048; C = 128;
    r0 = (f >> 1) * 64; c0 = (f & 1) * 64;
  }
#pragma unroll
  for (int p = 0; p < 16; ++p) {
    int idx = p * 256 + threadIdx.x;
    int r = idx >> 6, c = idx & 63;
    t[r][c] = in[(size_t)(r0 + r) * C + (c0 + c)];
  }
  __syncthreads();
#pragma unroll
  for (int p = 0; p < 16; ++p) {
    int idx = p * 256 + threadIdx.x;
    int c = idx >> 6, r = idx & 63;
    out[(size_t)(c0 + c) * R + (r0 + r)] = f2bf(t[r][c]);
  }
}

// ---------- bf16 GEMM: C = op(A @ Bt^T + bias) ----------
// Round-5 best config: 256x128 block tile, BK=32, 4 waves as 2x2, wave tile
// 128x64 (4x2 of 32x32x16 MFMA), 3-stage LDS pipeline (72KB -> 2 blk/CU),
// 1 barrier/k-step: [wait vmcnt(6)][s_barrier][issue k+2][compute k].
__global__ __launch_bounds__(256, 2) void k_gemm(const u16* __restrict__ A, const u16* __restrict__ Bt,
                                                 const float* __restrict__ bias, u16* __restrict__ C,
                                                 int M, int N, int K, int relu) {
  __shared__ __align__(16) u16 sm[36864];
  const int tid = threadIdx.x;
  const int l = tid & 63, w = tid >> 6;
  const int wm = w >> 1, wn = w & 1;
  const int m0 = blockIdx.y * 256, n0 = blockIdx.x * 128;

  const int kb = ((l & 3) ^ ((l >> 3) & 3)) * 16;
  const char* gA = (const char*)(A + (size_t)(m0 + w * 64 + (l >> 2)) * K) + kb;
  const char* gB = (const char*)(Bt + (size_t)(n0 + w * 32 + (l >> 2)) * K) + kb;
  const size_t chRows = (size_t)16 * K * 2;

  auto issue = [&](int kcB, int stg) {
    char* base = (char*)sm + stg * 24576;
    char* dA = base + (w * 4) * 1024 + l * 16;
    char* dB = base + 16384 + (w * 2) * 1024 + l * 16;
#pragma unroll
    for (int j = 0; j < 4; ++j) g2l16(gA + j * chRows + kcB, dA + j * 1024);
#pragma unroll
    for (int j = 0; j < 2; ++j) g2l16(gB + j * chRows + kcB, dB + j * 1024);
  };

  const int lm = l & 31;
  const int c0 = l >> 5;
  const int sw = (lm >> 1) & 3;

  f32x16 acc[4][2] = {};

  auto compute = [&](int stg) {
    const u16* As = sm + stg * 12288;
    const u16* Bs = As + 8192;
#pragma unroll
    for (int t = 0; t < 2; ++t) {
      const int cc = (((t << 1) + c0) ^ sw) * 8;
      bf16x8 a4[4], b2[2];
#pragma unroll
      for (int fm = 0; fm < 4; ++fm)
        a4[fm] = *(const bf16x8*)(As + (wm * 128 + fm * 32 + lm) * 32 + cc);
#pragma unroll
      for (int fn = 0; fn < 2; ++fn)
        b2[fn] = *(const bf16x8*)(Bs + (wn * 64 + fn * 32 + lm) * 32 + cc);
#pragma unroll
      for (int fm = 0; fm < 4; ++fm)
#pragma unroll
        for (int fn = 0; fn < 2; ++fn)
          acc[fm][fn] = __builtin_amdgcn_mfma_f32_32x32x16_bf16(a4[fm], b2[fn],
                                                                acc[fm][fn], 0, 0, 0);
    }
  };

  const int NK = K >> 5;
  issue(0, 0);
  issue(64, 1);
  int st = 0;
  for (int kt = 0; kt < NK; ++kt) {
    if (kt + 1 < NK) asm volatile("s_waitcnt vmcnt(6)" ::: "memory");
    else             asm volatile("s_waitcnt vmcnt(0)" ::: "memory");
    asm volatile("s_barrier" ::: "memory");
    if (kt + 2 < NK) {
      int stp = st + 2; if (stp >= 3) stp -= 3;
      issue((kt + 2) * 64, stp);
    }
    compute(st);
    ++st; if (st == 3) st = 0;
  }

  const int colb = n0 + wn * 64 + lm;
  const int rowb = m0 + wm * 128 + 4 * c0;
#pragma unroll
  for (int fn = 0; fn < 2; ++fn) {
    const float b = bias[colb + fn * 32];
#pragma unroll
    for (int fm = 0; fm < 4; ++fm)
#pragma unroll
      for (int g = 0; g < 4; ++g)
#pragma unroll
        for (int rr = 0; rr < 4; ++rr) {
          float v = acc[fm][fn][g * 4 + rr] + b;
          if (relu) v = fmaxf(v, 0.0f);
          C[(size_t)(rowb + fm * 32 + g * 8 + rr) * N + colb + fn * 32] = f2bf(v);
        }
  }
}

// ---------- split-K GEMM2 (N=128): 128x128 tile, 3-stage, 1 barrier/step ----------
__global__ __launch_bounds__(256, 2) void k_gemm_sk(const u16* __restrict__ A, const u16* __restrict__ Bt,
                                                    float* __restrict__ Ep, int K, int Ksplit) {
  __shared__ __align__(16) u16 sm[24576];
  const int tid = threadIdx.x;
  const int l = tid & 63, w = tid >> 6;
  const int wm = w >> 1, wn = w & 1;
  const int m0 = blockIdx.y * 128;
  const int split = blockIdx.x;
  const int k0s = split * Ksplit;

  const int kb = ((l & 3) ^ ((l >> 3) & 3)) * 16;
  const char* gA = (const char*)(A + (size_t)(m0 + w * 16 + (l >> 2)) * K + k0s) + kb;
  const char* gB = (const char*)(Bt + (size_t)(w * 16 + (l >> 2)) * K + k0s) + kb;
  const size_t radv = (size_t)64 * K * 2;

  auto issue = [&](int kcB, int stg) {
    char* base = (char*)sm + stg * 16384;
    char* dA = base + w * 1024 + l * 16;
    char* dB = base + 8192 + w * 1024 + l * 16;
    g2l16(gA + kcB, dA);
    g2l16(gA + radv + kcB, dA + 4096);
    g2l16(gB + kcB, dB);
    g2l16(gB + radv + kcB, dB + 4096);
  };

  const int lm = l & 31;
  const int c0 = l >> 5;
  const int sw = (lm >> 1) & 3;

  f32x16 acc[2][2] = {};

  auto compute = [&](int stg) {
    const u16* As = sm + stg * 8192;
    const u16* Bs = As + 4096;
#pragma unroll
    for (int t = 0; t < 2; ++t) {
      const int cc = (((t << 1) + c0) ^ sw) * 8;
      bf16x8 a2[2], b2[2];
#pragma unroll
      for (int fm = 0; fm < 2; ++fm) a2[fm] = *(const bf16x8*)(As + (wm * 64 + fm * 32 + lm) * 32 + cc);
#pragma unroll
      for (int fn = 0; fn < 2; ++fn) b2[fn] = *(const bf16x8*)(Bs + (wn * 64 + fn * 32 + lm) * 32 + cc);
#pragma unroll
      for (int fm = 0; fm < 2; ++fm)
#pragma unroll
        for (int fn = 0; fn < 2; ++fn)
          acc[fm][fn] = __builtin_amdgcn_mfma_f32_32x32x16_bf16(a2[fm], b2[fn],
                                                                acc[fm][fn], 0, 0, 0);
    }
  };

  const int NK = Ksplit >> 5;
  issue(0, 0);
  issue(64, 1);
  int st = 0;
  for (int kt = 0; kt < NK; ++kt) {
    if (kt + 1 < NK) asm volatile("s_waitcnt vmcnt(4)" ::: "memory");
    else             asm volatile("s_waitcnt vmcnt(0)" ::: "memory");
    asm volatile("s_barrier" ::: "memory");
    if (kt + 2 < NK) {
      int stp = st + 2; if (stp >= 3) stp -= 3;
      issue((kt + 2) * 64, stp);
    }
    compute(st);
    ++st; if (st == 3) st = 0;
  }

  const int colb = wn * 64 + lm;
  const int rowb = m0 + wm * 64 + 4 * c0;
#pragma unroll
  for (int fn = 0; fn < 2; ++fn)
#pragma unroll
    for (int fm = 0; fm < 2; ++fm)
#pragma unroll
      for (int g = 0; g < 4; ++g)
#pragma unroll
        for (int rr = 0; rr < 4; ++rr)
          Ep[((size_t)split * 8192 + rowb + fm * 32 + g * 8 + rr) * 128 + colb + fn * 32] =
              acc[fm][fn][g * 4 + rr];
}

// ---------- sum split-K partials + bias, L2-normalize rows, write bf16 f ----------
__global__ __launch_bounds__(256) void k_norm(const float* __restrict__ Ep,
                                              const float* __restrict__ b2, u16* __restrict__ F) {
  const int l = threadIdx.x & 63, w = threadIdx.x >> 6;
  const int row = blockIdx.x * 4 + w;
  const float2* base = (const float2*)Ep + (size_t)row * 64 + l;
  float x = 0.f, y = 0.f;
#pragma unroll
  for (int s = 0; s < 4; ++s) {
    float2 t = base[(size_t)s * (8192 * 64)];
    x += t.x; y += t.y;
  }
  x += b2[l * 2]; y += b2[l * 2 + 1];
  float sq = x * x + y * y;
#pragma unroll
  for (int off = 1; off < 64; off <<= 1) sq += __shfl_xor(sq, off);
  const float inv = 1.0f / sqrtf(sq);
  F[(size_t)row * 128 + l * 2] = f2bf(x * inv);
  F[(size_t)row * 128 + l * 2 + 1] = f2bf(y * inv);
}

// ---------- fused sim GEMM + fixed-max sumexp, register-cached A ----------
__global__ __launch_bounds__(256, 2) void k_sim(const u16* __restrict__ F, float* __restrict__ Sp) {
  __shared__ __align__(16) u16 sm[32768];  // [B0 32KB][A/B1 32KB]
  const int tid = threadIdx.x;
  const int l = tid & 63, w = tid >> 6;
  const int wm = w >> 1, wn = w & 1;
  const int lm = l & 31, c0 = l >> 5;
  const int r0 = blockIdx.y * 128;
  const int cb0 = blockIdx.x * 1024;

  u16* B0 = sm;
  u16* AB1 = sm + 16384;

  const int srow0 = tid >> 4;
  const int schunk = tid & 15;
  auto stage = [&](const u16* src, u16* dst) {
#pragma unroll
    for (int j = 0; j < 8; ++j) {
      const int row = j * 16 + srow0;
      const int lc = schunk ^ (row & 7);
      g2l16((const char*)(src + (size_t)row * 128) + lc * 16,
            (char*)dst + j * 4096 + tid * 16);
    }
  };

  stage(F + (size_t)r0 * 128, AB1);
  asm volatile("s_waitcnt vmcnt(0)" ::: "memory");
  __syncthreads();

  bf16x8 a[2][8];
#pragma unroll
  for (int fm = 0; fm < 2; ++fm) {
    const int ra = wm * 64 + fm * 32 + lm;
#pragma unroll
    for (int kf = 0; kf < 8; ++kf)
      a[fm][kf] = *(const bf16x8*)(AB1 + ra * 128 + (((kf << 1) + c0) ^ (ra & 7)) * 8);
  }
  asm volatile("s_waitcnt lgkmcnt(0)" ::: "memory");

  stage(F + (size_t)cb0 * 128, B0);

  const float S2 = INVT * L2E;
  const int rB = wn * 64 + lm;
  f32x16 runS[2] = {};

#pragma unroll 1
  for (int p = 0; p < 8; ++p) {
    asm volatile("s_waitcnt vmcnt(0)" ::: "memory");
    asm volatile("s_barrier" ::: "memory");
    if (p < 7) stage(F + (size_t)(cb0 + (p + 1) * 128) * 128, (p & 1) ? B0 : AB1);
    const u16* Bs = (p & 1) ? AB1 : B0;

    f32x16 acc[2][2] = {};
#pragma unroll
    for (int kf = 0; kf < 8; ++kf) {
      const int kc = (kf << 1) + c0;
      bf16x8 b0v = *(const bf16x8*)(Bs + rB * 128 + (kc ^ (rB & 7)) * 8);
      bf16x8 b1v = *(const bf16x8*)(Bs + (rB + 32) * 128 + (kc ^ ((rB + 32) & 7)) * 8);
      acc[0][0] = __builtin_amdgcn_mfma_f32_32x32x16_bf16(a[0][kf], b0v, acc[0][0], 0, 0, 0);
      acc[0][1] = __builtin_amdgcn_mfma_f32_32x32x16_bf16(a[0][kf], b1v, acc[0][1], 0, 0, 0);
      acc[1][0] = __builtin_amdgcn_mfma_f32_32x32x16_bf16(a[1][kf], b0v, acc[1][0], 0, 0, 0);
      acc[1][1] = __builtin_amdgcn_mfma_f32_32x32x16_bf16(a[1][kf], b1v, acc[1][1], 0, 0, 0);
    }

    const int cp = cb0 + p * 128;
    if (cp == r0) {
#pragma unroll
      for (int fm = 0; fm < 2; ++fm)
#pragma unroll
        for (int fn = 0; fn < 2; ++fn) {
          const int rcol = wn * 64 + fn * 32 + lm;
#pragma unroll
          for (int r = 0; r < 16; ++r) {
            const int rrow = wm * 64 + fm * 32 + (r & 3) + 8 * (r >> 2) + 4 * c0;
            float e = exp2f(fmaf(acc[fm][fn][r], S2, -S2));
            if (rrow == rcol) e = 0.f;
            runS[fm][r] += e;
          }
        }
    } else {
#pragma unroll
      for (int fm = 0; fm < 2; ++fm)
#pragma unroll
        for (int fn = 0; fn < 2; ++fn)
#pragma unroll
          for (int r = 0; r < 16; ++r)
            runS[fm][r] += exp2f(fmaf(acc[fm][fn][r], S2, -S2));
    }
  }

#pragma unroll
  for (int fm = 0; fm < 2; ++fm)
#pragma unroll
    for (int r = 0; r < 16; ++r) {
      float s = runS[fm][r];
      s += __shfl_xor(s, 1);
      s += __shfl_xor(s, 2);
      s += __shfl_xor(s, 4);
      s += __shfl_xor(s, 8);
      s += __shfl_xor(s, 16);
      runS[fm][r] = s;
    }

  __syncthreads();
  float* red = (float*)sm;
  if (wn == 0) {
    if (lm == 0) {
#pragma unroll
      for (int fm = 0; fm < 2; ++fm)
#pragma unroll
        for (int r = 0; r < 16; ++r)
          red[wm * 64 + fm * 32 + (r & 3) + 8 * (r >> 2) + 4 * c0] = runS[fm][r];
    }
  }
  __syncthreads();
  if (wn == 1 && lm == 0) {
#pragma unroll
    for (int fm = 0; fm < 2; ++fm)
#pragma unroll
      for (int r = 0; r < 16; ++r) {
        const int rr = wm * 64 + fm * 32 + (r & 3) + 8 * (r >> 2) + 4 * c0;
        Sp[(size_t)blockIdx.x * 8192 + r0 + rr] = red[rr] + runS[fm][r];
      }
  }
}

// ---------- merge chunk partials, compute pos, reduce mean(lse - pos) ----------
__global__ __launch_bounds__(256) void k_combine(const float* __restrict__ Sp,
                                                 const u16* __restrict__ F,
                                                 float* __restrict__ out) {
  const int r = blockIdx.x * 256 + threadIdx.x;
  float S = 0.f;
#pragma unroll
  for (int c = 0; c < 8; ++c) S += Sp[c * 8192 + r];
  const float lse = INVT + logf(S);
  const int par = (r + 4096) & 8191;
  const bf16x8* a = (const bf16x8*)(F + (size_t)r * 128);
  const bf16x8* b = (const bf16x8*)(F + (size_t)par * 128);
  float dot = 0.f;
#pragma unroll
  for (int k = 0; k < 16; ++k) {
    bf16x8 va = a[k], vb = b[k];
#pragma unroll
    for (int j = 0; j < 8; ++j) dot = fmaf((float)va[j], (float)vb[j], dot);
  }
  float contrib = lse - dot * INVT;
#pragma unroll
  for (int off = 1; off < 64; off <<= 1) contrib += __shfl_xor(contrib, off);
  if ((threadIdx.x & 63) == 0) atomicAdd(out, contrib * (1.0f / 8192.0f));
}

extern "C" void kernel_launch(void* const* d_in, const int* in_sizes, int n_in,
                              void* d_out, int out_size, void* d_ws, size_t ws_size,
                              hipStream_t stream) {
  const float* input1 = (const float*)d_in[0];
  const float* input2 = (const float*)d_in[1];
  const float* W0 = (const float*)d_in[2];
  const float* b0 = (const float*)d_in[3];
  const float* W1 = (const float*)d_in[4];
  const float* b1 = (const float*)d_in[5];
  const float* W2 = (const float*)d_in[6];
  const float* b2 = (const float*)d_in[7];
  float* out = (float*)d_out;
  char* ws = (char*)d_ws;

  u16* Xb = (u16*)(ws + 0);              // [8192][2048] bf16; reused as H2
  u16* H1 = (u16*)(ws + 33554432);
  u16* W0T = (u16*)(ws + 67108864);
  u16* W1T = (u16*)(ws + 75497472);
  float* Ep = (float*)(ws + 67108864);   // [4][8192][128] fp32, overlays dead W0T/W1T
  u16* W2T = (u16*)(ws + 83886080);
  float* Sp = (float*)(ws + 83886080);   // [8][8192] fp32, overlays W2T after sk
  u16* Ff = (u16*)(ws + 84410368);
  u16* H2 = Xb;

  hipMemsetAsync(d_out, 0, sizeof(float), stream);
  k_prep<<<18496, 256, 0, stream>>>(input1, input2, Xb, W0, W0T, W1, W1T, W2, W2T);
  k_gemm<<<dim3(16, 32), 256, 0, stream>>>(Xb, W0T, b0, H1, 8192, 2048, 2048, 1);
  k_gemm<<<dim3(16, 32), 256, 0, stream>>>(H1, W1T, b1, H2, 8192, 2048, 2048, 0);
  k_gemm_sk<<<dim3(4, 64), 256, 0, stream>>>(H2, W2T, Ep, 2048, 512);
  k_norm<<<2048, 256, 0, stream>>>(Ep, b2, Ff);
  k_sim<<<dim3(8, 64), 256, 0, stream>>>(Ff, Sp);
  k_combine<<<32, 256, 0, stream>>>(Sp, Ff, out);
}